// Round 10
// baseline (333.305 us; speedup 1.0000x reference)
//
#include <hip/hip_runtime.h>
#include <hip/hip_bf16.h>

// Problem constants (fixed by reference setup_inputs)
constexpr int NN   = 50000;    // nodes
constexpr int NE   = 600000;   // edges
constexpr int NRBF = 50;       // rbf features
constexpr int DIM  = 128;      // embedding dim
constexpr float CUT = 5.0f;
constexpr float PI_F = 3.14159265358979323846f;

constexpr int CAP = 32;        // bucket capacity (active degree ~Poisson(11.6); ovf fallback)

// Workspace layout (byte offsets). Total ~18 MB.
// R10: bucket entry packed to int2 {eid<<7|tau, cc_bits} — bit-exact (eid<2^20,
// tau<100<2^7), halves scattered-store bytes and the gather's ebuf traffic.
constexpr size_t OFF_DEG   = 0;                                 // [NN] int
constexpr size_t OFF_OVFC  = (size_t)NN * 4;                    // [1] int (memset covers both)
constexpr size_t OFF_EBUF  = 200960;                            // [NN*CAP] int2 (12.8 MB), 8-B aligned
constexpr size_t OFF_POS   = OFF_EBUF + (size_t)NN * CAP * 8;   // [NE] int (2.4 MB)
constexpr size_t OFF_OVF   = OFF_POS  + (size_t)NE * 4;         // [NE] int (2.4 MB)
constexpr size_t OFF_WAUG  = OFF_OVF  + (size_t)NE * 4;         // [128*64] bf16 (16 KB)
constexpr size_t OFF_EPERM = OFF_WAUG + 128 * 64 * 2;           // [100*128] bf16 permuted (25.6 KB)
constexpr size_t OFF_WCB   = OFF_EPERM + 100 * 128 * 2;         // [128*256] bf16 W_c (64 KB)

// emb_perm PERMUTED layout: position p holds dim delta(p) = 16*(p&7) + (p>>3).
// Lane c's positions 8c..8c+7 <-> dims {16q + c} = exactly its MFMA-D column across nt.

typedef __attribute__((ext_vector_type(4))) float f32x4;
typedef __attribute__((ext_vector_type(8))) short short8;

__device__ __forceinline__ float bf2f(unsigned short u) {
    return __uint_as_float(((unsigned int)u) << 16);
}
__device__ __forceinline__ unsigned short f2bf(float f) {
    return __bfloat16_as_ushort(__float2bfloat16(f));
}

// ---------------------------------------------------------------------------
// Kernel 1a (bp_count): the ATOMIC half of bucketing, isolated for profiling.
// Per edge: dist -> atomicAdd(deg[dst]) -> coalesced pos[e] store. Low tids
// also emit the small weights (W_aug/emb_perm/W_cb), as before.
// R9 ledger: the fused bucket_prep is ~140-148 us (invisible below the top-5
// cutoff) vs a <40 us traffic model — this split makes the cost attributable.
// ---------------------------------------------------------------------------
__global__ __launch_bounds__(256)
void bp_count(const float* __restrict__ dist, const int* __restrict__ dst,
              int* __restrict__ deg, int* __restrict__ pos,
              const float* __restrict__ W_e, const float* __restrict__ b_e,
              const float* __restrict__ emb, const float* __restrict__ W_c,
              unsigned short* __restrict__ W_aug, unsigned short* __restrict__ emb_perm,
              unsigned short* __restrict__ W_cb)
{
    const int e = blockIdx.x * 256 + threadIdx.x;

    if (e < NE) {
        const float dd = dist[e];
        if (dd < CUT)
            pos[e] = atomicAdd(&deg[dst[e]], 1);   // inactive: pos stays garbage (unused)
    }

    // small-weight prep, folded in (tids < 53760)
    if (e < 128 * 64) {
        const int d = e >> 6, k = e & 63;
        float v = 0.0f;
        if (k < NRBF)       v = W_e[d * NRBF + k];
        else if (k == NRBF) v = b_e[d];
        W_aug[e] = f2bf(v);
    } else if (e < 128 * 64 + 100 * 128) {
        const int i = e - 128 * 64;
        const int tau = i >> 7, p = i & 127;
        const int d = 16 * (p & 7) + (p >> 3);
        emb_perm[i] = f2bf(emb[tau * DIM + d]);
    } else if (e < 128 * 64 + 100 * 128 + 128 * 256) {
        const int i = e - (128 * 64 + 100 * 128);
        W_cb[i] = f2bf(W_c[i]);                    // row-major [128][256], same index
    }
}

// ---------------------------------------------------------------------------
// Kernel 1b (bp_place): the SCATTER half. No atomics in the common path; the
// packed int2 store is fire-and-forget — pure scatter-line throughput at full
// TLP. Overflow edges (pos >= CAP, ~never) go to the ovf list.
// ---------------------------------------------------------------------------
__global__ __launch_bounds__(256)
void bp_place(const float* __restrict__ dist, const int* __restrict__ dst,
              const int* __restrict__ src, const int* __restrict__ node_type,
              const int* __restrict__ pos, int2* __restrict__ ebuf,
              int* __restrict__ ovf, int* __restrict__ ovf_cnt)
{
    const int e = blockIdx.x * 256 + threadIdx.x;
    if (e >= NE) return;
    const float dd = dist[e];
    if (dd >= CUT) return;
    const int p = pos[e];
    if (p < CAP) {
        const float w = 0.5f * (__cosf(dd * (PI_F / CUT)) + 1.0f);
        const int tau = node_type[src[e]];
        ebuf[(size_t)dst[e] * CAP + p] = make_int2((e << 7) | tau, __float_as_int(w));
    } else {
        ovf[atomicAdd(ovf_cnt, 1)] = e;
    }
}

// ---------------------------------------------------------------------------
// Fused gather helpers. Arithmetic is BIT-IDENTICAL to the proven R9 path
// (int2 unpack only: eid = x>>7, tau = x&127, cc = f32 bits unchanged).
// ---------------------------------------------------------------------------
struct NodeLoad {
    float2 r0, r1, r2, r3, q0, q1, q2, q3;   // raw rbf float2s for round 0
    float  ccl;
    int    degn;
    int    mb;
};

__device__ __forceinline__ void issue_node(const int2* __restrict__ eb_s,
                                           const int* __restrict__ deg_s,
                                           const float* __restrict__ rbf,
                                           int nl, int c, int g, NodeLoad& L)
{
    const int dn = deg_s[nl];
    L.degn = dn < CAP ? dn : CAP;
    L.mb   = nl * 32;
    int ea = 0; L.ccl = 0.0f;
    if (c < L.degn) {                         // round-0 slot = c
        const int2 eb = eb_s[L.mb + c];
        ea    = eb.x >> 7;
        L.ccl = __int_as_float(eb.y);
    }
    const float2* rp2 = (const float2*)(rbf + (size_t)ea * NRBF);  // ea=0 inactive: safe
    L.r0 = rp2[4 * g];     L.r1 = rp2[4 * g + 1];
    L.r2 = rp2[4 * g + 2]; L.r3 = rp2[4 * g + 3];
    L.q0 = make_float2(0.f, 0.f); L.q1 = L.q0; L.q2 = L.q0; L.q3 = L.q0;
    if (g < 2) {
        L.q0 = rp2[16 + 4 * g]; L.q1 = rp2[17 + 4 * g];
        L.q2 = rp2[18 + 4 * g]; L.q3 = rp2[19 + 4 * g];
    } else if (g == 2) {
        L.q0 = rp2[24];                        // k48,k49
    }
}

__device__ __forceinline__ void round_compute(
    float ccl, float2 r0, float2 r1, float2 r2, float2 r3,
    float2 q0, float2 q1, float2 q2, float2 q3,
    int j0, int degn, int mb, int c, int g,
    const unsigned short* __restrict__ wlds, const int2* __restrict__ eb_s,
    const unsigned short* __restrict__ emb_perm, float v[8])
{
    short8 a0, a1;
    a0[0] = (short)f2bf(ccl * r0.x); a0[1] = (short)f2bf(ccl * r0.y);
    a0[2] = (short)f2bf(ccl * r1.x); a0[3] = (short)f2bf(ccl * r1.y);
    a0[4] = (short)f2bf(ccl * r2.x); a0[5] = (short)f2bf(ccl * r2.y);
    a0[6] = (short)f2bf(ccl * r3.x); a0[7] = (short)f2bf(ccl * r3.y);
    a1[0] = (short)f2bf(ccl * q0.x); a1[1] = (short)f2bf(ccl * q0.y);
    a1[2] = (short)f2bf(ccl * q1.x); a1[3] = (short)f2bf(ccl * q1.y);
    a1[4] = (short)f2bf(ccl * q2.x); a1[5] = (short)f2bf(ccl * q2.y);
    a1[6] = (short)f2bf(ccl * q3.x); a1[7] = (short)f2bf(ccl * q3.y);
    if (g == 2) {                              // k50 = cc (b_e hook), k51+ = 0
        a1[2] = (short)f2bf(ccl);
        a1[3] = 0; a1[4] = 0; a1[5] = 0; a1[6] = 0; a1[7] = 0;
    }

    f32x4 acc[8] = {};
    #pragma unroll
    for (int nt = 0; nt < 8; ++nt) {
        const short8 bf0 = *(const short8*)((const char*)wlds + (nt * 16 + c) * 144 + g * 16);
        acc[nt] = __builtin_amdgcn_mfma_f32_16x16x32_bf16(a0, bf0, acc[nt], 0, 0, 0);
    }
    #pragma unroll
    for (int nt = 0; nt < 8; ++nt) {
        const short8 bf1 = *(const short8*)((const char*)wlds + (nt * 16 + c) * 144 + (4 + g) * 16);
        acc[nt] = __builtin_amdgcn_mfma_f32_16x16x32_bf16(a1, bf1, acc[nt], 0, 0, 0);
    }

    #pragma unroll
    for (int r = 0; r < 4; ++r) {
        const int jr = j0 + 4 * g + r;
        if (jr < degn) {
            const int rw = eb_s[mb + jr].x & 127;          // tau
            const int4 em = *(const int4*)(emb_perm + rw * DIM + 8 * c);
            const unsigned int* ep = (const unsigned int*)&em;
            #pragma unroll
            for (int q = 0; q < 4; ++q) {
                const float m0 = bf2f((unsigned short)(ep[q] & 0xffff));
                const float m1 = bf2f((unsigned short)(ep[q] >> 16));
                v[2 * q]     += bf2f(f2bf(acc[2 * q][r]     * m0));   // bf16-round: bit-
                v[2 * q + 1] += bf2f(f2bf(acc[2 * q + 1][r] * m1));   // identical to msg path
            }
        }
    }
}

__device__ __forceinline__ void compute_node(
    const NodeLoad& L, int c, int g,
    const unsigned short* __restrict__ wlds, const int2* __restrict__ eb_s,
    const unsigned short* __restrict__ emb_perm, const float* __restrict__ rbf,
    float v[8])
{
    round_compute(L.ccl, L.r0, L.r1, L.r2, L.r3, L.q0, L.q1, L.q2, L.q3,
                  0, L.degn, L.mb, c, g, wlds, eb_s, emb_perm, v);
    if (L.degn > 16) {                         // rare (P ~ 1%): round 1, slots 16..31
        int ea = 0; float ccl = 0.0f;
        const int slot = 16 + c;
        if (slot < L.degn) {
            const int2 eb = eb_s[L.mb + slot];
            ea  = eb.x >> 7;
            ccl = __int_as_float(eb.y);
        }
        const float2* rp2 = (const float2*)(rbf + (size_t)ea * NRBF);
        const float2 r0 = rp2[4 * g],     r1 = rp2[4 * g + 1];
        const float2 r2 = rp2[4 * g + 2], r3 = rp2[4 * g + 3];
        float2 q0 = make_float2(0.f, 0.f), q1 = q0, q2 = q0, q3 = q0;
        if (g < 2) {
            q0 = rp2[16 + 4 * g]; q1 = rp2[17 + 4 * g];
            q2 = rp2[18 + 4 * g]; q3 = rp2[19 + 4 * g];
        } else if (g == 2) {
            q0 = rp2[24];
        }
        round_compute(ccl, r0, r1, r2, r3, q0, q1, q2, q3,
                      16, L.degn, L.mb, c, g, wlds, eb_s, emb_perm, v);
    }
}

__device__ __forceinline__ void finish_node_lds(
    float v[8], int n, int nl, int c, int g, int ocnt,
    const int* __restrict__ ovf, const int* __restrict__ dst,
    const float* __restrict__ dist, const int* __restrict__ src,
    const int* __restrict__ node_type, const float* __restrict__ rbf,
    const unsigned short* __restrict__ W_aug_g,
    const unsigned short* __restrict__ emb_perm,
    unsigned short* __restrict__ cat_s /* [16][264] */)
{
    // Overflow fallback (deg > CAP): essentially never taken, kept for correctness.
    for (int j = 0; j < ocnt; ++j) {
        const int e = ovf[j];
        if (dst[e] != n) continue;
        const float dd  = dist[e];
        const float ccl = 0.5f * (__cosf(dd * (PI_F / CUT)) + 1.0f);
        if (g == 0) {
            const int tau = node_type[src[e]];
            const float* rp = rbf + (size_t)e * NRBF;
            const float ccb16 = bf2f(f2bf(ccl));
            #pragma unroll
            for (int q = 0; q < 8; ++q) {
                const int d = 16 * q + c;
                float s = bf2f(W_aug_g[d * 64 + NRBF]) * ccb16;       // b_e * cc
                for (int k = 0; k < NRBF; ++k)
                    s += bf2f(W_aug_g[d * 64 + k]) * bf2f(f2bf(ccl * rp[k]));
                v[q] += bf2f(f2bf(s * bf2f(emb_perm[tau * DIM + 8 * c + q])));
            }
        }
    }

    #pragma unroll
    for (int q = 0; q < 8; ++q) {
        v[q] += __shfl_xor(v[q], 16);
        v[q] += __shfl_xor(v[q], 32);
    }

    float s0 = v[0], s1 = v[1];
    if (g == 1)      { s0 = v[2]; s1 = v[3]; }
    else if (g == 2) { s0 = v[4]; s1 = v[5]; }
    else if (g == 3) { s0 = v[6]; s1 = v[7]; }
    // xi -> LDS cat rows (k index 128 + dim): identical bits to the old global xi.
    cat_s[nl * 264 + 128 + 32 * g + c]      = f2bf(s0);
    cat_s[nl * 264 + 128 + 32 * g + 16 + c] = f2bf(s1);
}

// ---------------------------------------------------------------------------
// Kernel 2 (FULLY FUSED edge_msg + gather_sum + combine — R9-proven structure,
// int2 buckets). 16 nodes/block (NN = 3125 x 16 exactly); gather = 4 serial
// nodes/wave; combine = proven fragment mapping, all 16 A-rows real.
// ---------------------------------------------------------------------------
__global__ __launch_bounds__(256)
void gather_combine(const float* __restrict__ rbf,
                    const int* __restrict__ deg, const int2* __restrict__ ebuf,
                    const unsigned short* __restrict__ W_aug,
                    const unsigned short* __restrict__ emb_perm,
                    const unsigned short* __restrict__ W_cb,
                    const int* __restrict__ ovf, const int* __restrict__ ovf_cnt,
                    const int* __restrict__ dst, const float* __restrict__ dist,
                    const int* __restrict__ src, const int* __restrict__ node_type,
                    const float* __restrict__ x_nodes, const float* __restrict__ b_c,
                    float* __restrict__ out)
{
    __shared__ __align__(16) unsigned short wlds[128 * 72];   // 18 KB W_aug tile
    __shared__ __align__(16) unsigned short cat_s[16 * 264];  // 8.25 KB [x|xi] bf16
    __shared__ int2 eb_s[16 * 32];                            // 4 KB packed slots
    __shared__ int  deg_s[16];

    const int t = threadIdx.x, l = t & 63;
    const int wv = t >> 6;
    const int c = l & 15, g = l >> 4;
    const int n0 = blockIdx.x * 16;

    // ---- block-level prestage (one sync) ----
    {
        eb_s[t]       = ebuf[(size_t)n0 * CAP + t];        // 16 nodes x 32 slots,
        eb_s[256 + t] = ebuf[(size_t)n0 * CAP + 256 + t];  // coalesced 8-B
        if (t < 16) deg_s[t] = deg[n0 + t];
        #pragma unroll
        for (int i = 0; i < 4; ++i) {
            const int ch = i * 256 + t;            // 1024 x 16-B chunks
            const int row = ch >> 3, f = ch & 7;
            *(int4*)((char*)wlds + row * 144 + f * 16) = ((const int4*)W_aug)[ch];
        }
        // x_nodes -> cat_s rows 0..15, k 0..127 (bf16). 16 thr/node x 8 f32 each.
        const int nl = t >> 4, k0 = (t & 15) * 8;
        const float4 xv0 = *(const float4*)(x_nodes + (size_t)(n0 + nl) * DIM + k0);
        const float4 xv1 = *(const float4*)(x_nodes + (size_t)(n0 + nl) * DIM + k0 + 4);
        unsigned short* dp = &cat_s[nl * 264 + k0];
        *(ushort2*)&dp[0] = make_ushort2(f2bf(xv0.x), f2bf(xv0.y));
        *(ushort2*)&dp[2] = make_ushort2(f2bf(xv0.z), f2bf(xv0.w));
        *(ushort2*)&dp[4] = make_ushort2(f2bf(xv1.x), f2bf(xv1.y));
        *(ushort2*)&dp[6] = make_ushort2(f2bf(xv1.z), f2bf(xv1.w));
    }
    __syncthreads();
    const int ocnt = ovf_cnt[0];

    // ---- gather phase: this wave's 4 nodes, serial (proven structure) ----
    const int nbase = wv * 4;
    #pragma unroll
    for (int ni = 0; ni < 4; ++ni) {
        const int nl = nbase + ni;
        NodeLoad L;
        issue_node(eb_s, deg_s, rbf, nl, c, g, L);
        float v[8] = {};
        compute_node(L, c, g, wlds, eb_s, emb_perm, rbf, v);
        finish_node_lds(v, n0 + nl, nl, c, g, ocnt, ovf, dst, dist, src,
                        node_type, rbf, W_aug, emb_perm, cat_s);
    }
    __syncthreads();

    // ---- combine phase: wave wv owns out-dim tiles 2wv, 2wv+1; A rows = 16
    // real nodes. Proven fragment mapping, K ascending. ----
    f32x4 acc0 = {}, acc1 = {};
    const int t0 = wv * 2, t1 = wv * 2 + 1;
    #pragma unroll
    for (int kc = 0; kc < 8; ++kc) {
        const int ko = kc * 32 + g * 8;
        const short8 af = *(const short8*)&cat_s[c * 264 + ko];
        const short8 b0 = *(const short8*)(W_cb + (size_t)(t0 * 16 + c) * 256 + ko);
        const short8 b1 = *(const short8*)(W_cb + (size_t)(t1 * 16 + c) * 256 + ko);
        acc0 = __builtin_amdgcn_mfma_f32_16x16x32_bf16(af, b0, acc0, 0, 0, 0);
        acc1 = __builtin_amdgcn_mfma_f32_16x16x32_bf16(af, b1, acc1, 0, 0, 0);
    }
    // D: lane (c,g) reg r -> node 4g+r (all 16 real), dim tile*16+c.
    const float bc0 = b_c[t0 * 16 + c];
    const float bc1 = b_c[t1 * 16 + c];
    #pragma unroll
    for (int r = 0; r < 4; ++r) {
        const int node = 4 * g + r;
        out[(size_t)(n0 + node) * DIM + t0 * 16 + c] = acc0[r] + bc0;
        out[(size_t)(n0 + node) * DIM + t1 * 16 + c] = acc1[r] + bc1;
    }
}

// ---------------------------------------------------------------------------
extern "C" void kernel_launch(void* const* d_in, const int* in_sizes, int n_in,
                              void* d_out, int out_size, void* d_ws, size_t ws_size,
                              hipStream_t stream)
{
    const int*   node_type = (const int*)  d_in[0];
    const float* x_nodes   = (const float*)d_in[1];
    const int*   src       = (const int*)  d_in[2];
    const int*   dst       = (const int*)  d_in[3];
    const float* rbf       = (const float*)d_in[4];
    const float* dist      = (const float*)d_in[5];
    const float* emb       = (const float*)d_in[6];
    const float* W_e       = (const float*)d_in[7];
    const float* b_e       = (const float*)d_in[8];
    const float* W_c       = (const float*)d_in[9];
    const float* b_c       = (const float*)d_in[10];
    float* out = (float*)d_out;

    char* ws = (char*)d_ws;
    int*            deg      = (int*)(ws + OFF_DEG);
    int*            ovf_cnt  = (int*)(ws + OFF_OVFC);
    int2*           ebuf     = (int2*)(ws + OFF_EBUF);
    int*            pos      = (int*)(ws + OFF_POS);
    int*            ovf      = (int*)(ws + OFF_OVF);
    unsigned short* W_aug    = (unsigned short*)(ws + OFF_WAUG);
    unsigned short* emb_perm = (unsigned short*)(ws + OFF_EPERM);
    unsigned short* W_cb     = (unsigned short*)(ws + OFF_WCB);

    hipMemsetAsync(deg, 0, (NN + 1) * sizeof(int), stream);

    bp_count<<<(NE + 255) / 256, 256, 0, stream>>>(
        dist, dst, deg, pos, W_e, b_e, emb, W_c, W_aug, emb_perm, W_cb);

    bp_place<<<(NE + 255) / 256, 256, 0, stream>>>(
        dist, dst, src, node_type, pos, ebuf, ovf, ovf_cnt);

    gather_combine<<<NN / 16, 256, 0, stream>>>(
        rbf, deg, ebuf, W_aug, emb_perm, W_cb,
        ovf, ovf_cnt, dst, dist, src, node_type, x_nodes, b_c, out);
}